// Round 4
// baseline (493.187 us; speedup 1.0000x reference)
//
#include <hip/hip_runtime.h>
#include <hip/hip_fp16.h>

#define N_NODES 100000
#define N_EDGES 1600000
#define DIM 64
#define NEG_SLOPE 0.01f

// ---- preprocessing bucket geometry ----
#define PNODES 256            // nodes per preproc bucket
#define PNB 391               // ceil(100000/256)
#define BCAP 4608             // slab capacity per bucket (avg fill ~4092, sd ~64)
#define BLOCKS1 512           // scatter blocks (2 per CU)
#define THREADS1 512          // 8 waves
#define EPB (N_EDGES / BLOCKS1)   // 3125 exactly

// ---- aggregation tile geometry ----
#define FNODES 64             // nodes per agg block
#define FNB 1563              // ceil(100000/64)
#define QELEM 16              // features per quarter slice
#define QSTRIDE ((size_t)N_NODES * QELEM)   // halves per slice (3.2 MB)

typedef _Float16 half8 __attribute__((ext_vector_type(8)));
typedef float float4v __attribute__((ext_vector_type(4)));

// ---- weight prep: W fp32 [k][f] -> WT16 fp16 transposed [f][k], 4 layers ----
// blocks 4..7 zero gcur (folds the memset dispatch in here)
__global__ void prep_weights(const float* __restrict__ W0, const float* __restrict__ W1,
                             const float* __restrict__ W2, const float* __restrict__ W3,
                             __half* __restrict__ WT16, int* __restrict__ gcur) {
    if (blockIdx.x < 4) {
        const float* Ws[4] = {W0, W1, W2, W3};
        const float* W = Ws[blockIdx.x];
        __half* dst = WT16 + (size_t)blockIdx.x * DIM * DIM;
        for (int e = threadIdx.x; e < DIM * DIM; e += 256) {
            int k = e >> 6, f = e & 63;
            dst[f * DIM + k] = __float2half(W[e]);
        }
    } else {
        for (int i = (blockIdx.x - 4) * 256 + threadIdx.x; i < PNB * 16; i += 4 * 256)
            gcur[i] = 0;
    }
}

// ---- pass 1: LDS counting-sort scatter (256-node buckets, staged writeout) ----
__global__ __launch_bounds__(THREADS1) void bucket_scatter(const int* __restrict__ src,
                                                           const int* __restrict__ dst,
                                                           int* __restrict__ gcur,   // stride 16 (64B pad)
                                                           int* __restrict__ bdata) {
    __shared__ int cnt[PNB];
    __shared__ int lexcl[PNB];
    __shared__ int base[PNB];
    __shared__ int wsum[THREADS1 / 64];
    __shared__ int sorted_e[EPB];
    __shared__ unsigned short sorted_b[EPB];

    const int tid = threadIdx.x;
    for (int i = tid; i < PNB; i += THREADS1) cnt[i] = 0;
    __syncthreads();

    const int e0 = blockIdx.x * EPB;
    const int e1 = e0 + EPB;

    for (int e = e0 + tid; e < e1; e += THREADS1)
        atomicAdd(&cnt[dst[e] >> 8], 1);
    __syncthreads();

    // exclusive scan over PNB=391 counters: wave-level shfl scan + wave partials
    int v = (tid < PNB) ? cnt[tid] : 0;
    int incl = v;
#pragma unroll
    for (int s = 1; s < 64; s <<= 1) {
        int up = __shfl_up(incl, s, 64);
        if ((tid & 63) >= s) incl += up;
    }
    if ((tid & 63) == 63) wsum[tid >> 6] = incl;
    __syncthreads();
    int wpre = 0;
    for (int w = 0; w < (tid >> 6); ++w) wpre += wsum[w];
    if (tid < PNB) lexcl[tid] = wpre + incl - v;

    // global slab reservation; reuse cnt as intra-block cursor
    for (int i = tid; i < PNB; i += THREADS1) {
        int c = cnt[i];
        base[i] = c ? atomicAdd(&gcur[i * 16], c) : 0;
        cnt[i] = 0;
    }
    __syncthreads();

    for (int e = e0 + tid; e < e1; e += THREADS1) {
        int d = dst[e];
        int b = d >> 8;
        int p = lexcl[b] + atomicAdd(&cnt[b], 1);
        sorted_e[p] = src[e] | ((d & 255) << 17);
        sorted_b[p] = (unsigned short)b;
    }
    __syncthreads();

    // coalesced writeout: runs of avg ~8-16 consecutive slots per bucket
    for (int i = tid; i < EPB; i += THREADS1) {
        int b = sorted_b[i];
        bdata[(size_t)b * BCAP + base[b] + (i - lexcl[b])] = sorted_e[i];
    }
}

// ---- pass 2: per-bucket counting sort -> offsets, dinv, csr (single-writer) ----
__global__ __launch_bounds__(256) void bucket_build(const int* __restrict__ bdata,
                                                    const int* __restrict__ gcur,
                                                    int* __restrict__ offsets,
                                                    float* __restrict__ dinv,
                                                    int* __restrict__ csr) {
    __shared__ int cnt[PNODES];
    __shared__ int excl[PNODES];
    __shared__ int part[256];
    const int tid = threadIdx.x;
    const int b = blockIdx.x;
    const int sz = gcur[b * 16];
    const int* bd = bdata + (size_t)b * BCAP;

    // cbase = sum of bucket sizes for buckets < b (parallel reduce, L2-hot)
    int s = 0;
    for (int i = tid; i < b; i += 256) s += gcur[i * 16];
    part[tid] = s;
    __syncthreads();
    for (int st = 128; st > 0; st >>= 1) {
        if (tid < st) part[tid] += part[tid + st];
        __syncthreads();
    }
    const int cbase = part[0];
    __syncthreads();

    for (int i = tid; i < PNODES; i += 256) cnt[i] = 0;
    __syncthreads();
    for (int i = tid; i < sz; i += 256)
        atomicAdd(&cnt[bd[i] >> 17], 1);
    __syncthreads();
    if (tid == 0) {
        int run = 0;
        for (int j = 0; j < PNODES; ++j) { excl[j] = run; run += cnt[j]; }
    }
    __syncthreads();

    const int nb = b * PNODES;
    for (int i = tid; i < PNODES; i += 256) {
        int n = nb + i;
        if (n < N_NODES) {
            offsets[n] = cbase + excl[i];
            dinv[n] = rsqrtf((float)(cnt[i] + 1));   // deg incl self-loop
        }
    }
    if (b == PNB - 1 && tid == 0) offsets[N_NODES] = N_EDGES;

    for (int i = tid; i < PNODES; i += 256) cnt[i] = 0;   // reuse as cursor
    __syncthreads();
    for (int i = tid; i < sz; i += 256) {
        int v = bd[i];
        int l = v >> 17;
        int pos = cbase + excl[l] + atomicAdd(&cnt[l], 1);
        csr[pos] = (v & 0x1FFFF) << 4;   // element offset src*QELEM (quarter-major)
    }
}

// ---- staging helpers: load 8 fp16 features [koff..koff+8) of a node ----
__device__ __forceinline__ void stage_row8(__half* dst, const float* __restrict__ X,
                                           int node, int koff) {
    // input x: fp32 row-major [node][64]
    size_t off = (size_t)node * DIM + koff;
    float4 f0 = *(const float4*)(X + off);
    float4 f1 = *(const float4*)(X + off + 4);
    __half2 h0 = __floats2half2_rn(f0.x, f0.y);
    __half2 h1 = __floats2half2_rn(f0.z, f0.w);
    __half2 h2 = __floats2half2_rn(f1.x, f1.y);
    __half2 h3 = __floats2half2_rn(f1.z, f1.w);
    uint4 u;
    u.x = *(unsigned int*)&h0; u.y = *(unsigned int*)&h1;
    u.z = *(unsigned int*)&h2; u.w = *(unsigned int*)&h3;
    *(uint4*)dst = u;
}
__device__ __forceinline__ void stage_row8(__half* dst, const __half* __restrict__ X,
                                           int node, int koff) {
    // ACT16: fp16 quarter-major [q][node][16]
    const __half* p = X + (size_t)(koff >> 4) * QSTRIDE + (size_t)node * QELEM + (koff & 15);
    *(uint4*)dst = *(const uint4*)p;
}

// ---- MFMA fp16 matmul + dinv: G[q][r][j] = (half) dinv[r] * sum_k X[r,k] W[k,f] ----
#define XPAD 72
template <typename TIN>
__global__ __launch_bounds__(256) void mm_kernel(const TIN* __restrict__ X,
                                                 const __half* __restrict__ WT,  // [f][k] fp16
                                                 const float* __restrict__ dinv,
                                                 __half* __restrict__ G16) {    // quarter-major out
    __shared__ __align__(16) __half xs[64][XPAD];
    __shared__ __align__(16) __half ws[64][XPAD];
    const int t = threadIdx.x;
    const int rbase = blockIdx.x * 64;

    for (int c = t; c < 512; c += 256) {
        int row = c >> 3, koff = (c & 7) * 8;
        int grow = rbase + row;
        if (grow < N_NODES) {
            stage_row8(&xs[row][koff], X, grow, koff);
        } else {
            *(uint4*)&xs[row][koff] = make_uint4(0, 0, 0, 0);
        }
        // W tile is row-major [f][k]
        {
            const __half* p = WT + (size_t)row * DIM + koff;
            *(uint4*)&ws[row][koff] = *(const uint4*)p;
        }
    }
    __syncthreads();

    const int wave = t >> 6;
    const int lane = t & 63;
    const int qr = lane >> 4;     // accumulator row block
    const int c16 = lane & 15;    // node within 16
    const int n0 = wave * 16;

    half8 b0 = *(const half8*)&xs[n0 + c16][qr * 8];
    half8 b1 = *(const half8*)&xs[n0 + c16][32 + qr * 8];

    const int gnode = rbase + n0 + c16;
    float di = (gnode < N_NODES) ? dinv[gnode] : 0.f;

#pragma unroll
    for (int ft = 0; ft < 4; ++ft) {
        const int f0 = ft * 16;
        half8 a0 = *(const half8*)&ws[f0 + c16][qr * 8];
        half8 a1 = *(const half8*)&ws[f0 + c16][32 + qr * 8];
        float4v acc = {0.f, 0.f, 0.f, 0.f};
        acc = __builtin_amdgcn_mfma_f32_16x16x32_f16(a0, b0, acc, 0, 0, 0);
        acc = __builtin_amdgcn_mfma_f32_16x16x32_f16(a1, b1, acc, 0, 0, 0);
        if (gnode < N_NODES) {
            __half2 p0 = __floats2half2_rn(di * acc[0], di * acc[1]);
            __half2 p1 = __floats2half2_rn(di * acc[2], di * acc[3]);
            uint2 u;
            u.x = *(unsigned int*)&p0;
            u.y = *(unsigned int*)&p1;
            // features f0+qr*4 .. +3 -> quarter f0>>4, offset qr*4
            __half* gp = G16 + (size_t)(f0 >> 4) * QSTRIDE + (size_t)gnode * QELEM + qr * 4;
            *(uint2*)gp = u;
        }
    }
}

// ---------------- aggregation: pass-major feature-sliced gather ----------------
// grid = 4*FNB; block (q = bid/FNB, bucket = bid%FNB) aggregates feature
// quarter q (a 3.2 MB slice of Gin -> L2-resident per XCD) for 64 nodes.
// Per 32-lane group: one node; 16 slots x 2 lanes; 32B gathered per edge.
template <bool FINAL>
__global__ __launch_bounds__(256) void agg4(const __half* __restrict__ Gin,   // quarter-major
                                            const int* __restrict__ csr,     // src*QELEM
                                            const int* __restrict__ offsets,
                                            const float* __restrict__ dinv,
                                            const float* __restrict__ bias,
                                            void* __restrict__ outp) {
    const int bid = blockIdx.x;
    const int q = bid / FNB;
    const int bucket = bid - q * FNB;
    const int nb = bucket * FNODES;
    const __half* Gq = Gin + (size_t)q * QSTRIDE;

    const int t = threadIdx.x;
    const int wave = t >> 6;
    const int lane = t & 63;
    const int grp  = lane >> 5;        // node of the pair
    const int g    = lane & 31;
    const int slot = g >> 1;           // 0..15
    const int sub  = g & 1;            // 16B half of the 32B quarter
    const int fo   = sub * 8;          // feature offset within quarter (halves)

    for (int i = 0; i < 8; ++i) {
        const int lrow = wave * 16 + i * 2 + grp;   // 0..63 local row
        const int wid = nb + lrow;
        const bool valid = (wid < N_NODES);
        const int beg = valid ? offsets[wid] : 0;
        const int end = valid ? offsets[wid + 1] : 0;

        __half2 h0 = __float2half2_rn(0.f), h1 = h0, h2 = h0, h3 = h0;
        for (int e = beg + slot; e < end; e += 16) {
            int p0 = csr[e];
            float4 v0 = *(const float4*)(Gq + (size_t)p0 + fo);
            const __half2* hp = (const __half2*)&v0;
            h0 = __hadd2(h0, hp[0]);
            h1 = __hadd2(h1, hp[1]);
            h2 = __hadd2(h2, hp[2]);
            h3 = __hadd2(h3, hp[3]);
        }

        float acc[8];
        {
            float2 f;
            f = __half22float2(h0); acc[0] = f.x; acc[1] = f.y;
            f = __half22float2(h1); acc[2] = f.x; acc[3] = f.y;
            f = __half22float2(h2); acc[4] = f.x; acc[5] = f.y;
            f = __half22float2(h3); acc[6] = f.x; acc[7] = f.y;
        }
        // reduce 16 slots (lane bits 1..4), keep sub (bit 0) and grp (bit 5)
#pragma unroll
        for (int k = 0; k < 8; ++k) {
            acc[k] += __shfl_xor(acc[k], 2, 64);
            acc[k] += __shfl_xor(acc[k], 4, 64);
            acc[k] += __shfl_xor(acc[k], 8, 64);
            acc[k] += __shfl_xor(acc[k], 16, 64);
        }

        if (slot == 0 && valid) {   // lanes 0,1 (node A) and 32,33 (node B)
            // self-loop row quarter, exactly once, post-reduction
            float4 vs = *(const float4*)(Gq + (size_t)wid * QELEM + fo);
            {
                const __half2* hp = (const __half2*)&vs;
                float2 f0 = __half22float2(hp[0]);
                float2 f1 = __half22float2(hp[1]);
                float2 f2 = __half22float2(hp[2]);
                float2 f3 = __half22float2(hp[3]);
                acc[0] += f0.x; acc[1] += f0.y;
                acc[2] += f1.x; acc[3] += f1.y;
                acc[4] += f2.x; acc[5] += f2.y;
                acc[6] += f3.x; acc[7] += f3.y;
            }
            float di = dinv[wid];
            float4 bb0 = *(const float4*)(bias + q * QELEM + fo);
            float4 bb1 = *(const float4*)(bias + q * QELEM + fo + 4);
            float r[8];
            r[0] = di * acc[0] + bb0.x;
            r[1] = di * acc[1] + bb0.y;
            r[2] = di * acc[2] + bb0.z;
            r[3] = di * acc[3] + bb0.w;
            r[4] = di * acc[4] + bb1.x;
            r[5] = di * acc[5] + bb1.y;
            r[6] = di * acc[6] + bb1.z;
            r[7] = di * acc[7] + bb1.w;
#pragma unroll
            for (int k = 0; k < 8; ++k)
                r[k] = (r[k] >= 0.f) ? r[k] : NEG_SLOPE * r[k];

            if (FINAL) {
                float* out = (float*)outp;
                *(float4*)(out + (size_t)wid * DIM + q * QELEM + fo)     = make_float4(r[0], r[1], r[2], r[3]);
                *(float4*)(out + (size_t)wid * DIM + q * QELEM + fo + 4) = make_float4(r[4], r[5], r[6], r[7]);
            } else {
                __half* act = (__half*)outp;   // quarter-major ACT16
                __half2 q0 = __floats2half2_rn(r[0], r[1]);
                __half2 q1 = __floats2half2_rn(r[2], r[3]);
                __half2 q2 = __floats2half2_rn(r[4], r[5]);
                __half2 q3 = __floats2half2_rn(r[6], r[7]);
                uint4 u;
                u.x = *(unsigned int*)&q0;
                u.y = *(unsigned int*)&q1;
                u.z = *(unsigned int*)&q2;
                u.w = *(unsigned int*)&q3;
                *(uint4*)(act + (size_t)q * QSTRIDE + (size_t)wid * QELEM + fo) = u;
            }
        }
    }
}

extern "C" void kernel_launch(void* const* d_in, const int* in_sizes, int n_in,
                              void* d_out, int out_size, void* d_ws, size_t ws_size,
                              hipStream_t stream) {
    const float* x = (const float*)d_in[0];
    const int* ei = (const int*)d_in[1];
    const int* src = ei;
    const int* dst = ei + N_EDGES;
    const float* W[4] = {(const float*)d_in[2], (const float*)d_in[4],
                         (const float*)d_in[6], (const float*)d_in[8]};
    const float* b[4] = {(const float*)d_in[3], (const float*)d_in[5],
                         (const float*)d_in[7], (const float*)d_in[9]};
    float* out = (float*)d_out;

    char* ws = (char*)d_ws;
    size_t off = 0;
    auto alloc = [&](size_t bytes) -> void* {
        void* p = ws + off;
        off = (off + bytes + 255) & ~(size_t)255;
        return p;
    };
    __half* GA    = (__half*)alloc((size_t)N_NODES * DIM * sizeof(__half));   // 12.8 MB
    __half* GB    = (__half*)alloc((size_t)N_NODES * DIM * sizeof(__half));   // 12.8 MB
    __half* ACT16 = (__half*)alloc((size_t)N_NODES * DIM * sizeof(__half));   // 12.8 MB
    __half* WT16  = (__half*)alloc((size_t)4 * DIM * DIM * sizeof(__half));   // 32 KB
    int*   csr    = (int*)alloc((size_t)N_EDGES * sizeof(int));               // 6.4 MB
    int*   bdata  = (int*)alloc((size_t)PNB * BCAP * sizeof(int));            // 7.2 MB
    int*   gcur   = (int*)alloc((size_t)PNB * 16 * sizeof(int));              // 25 KB
    int*   offsets= (int*)alloc((size_t)(N_NODES + 1) * sizeof(int));
    float* dinv   = (float*)alloc((size_t)N_NODES * sizeof(float));

    // prep_weights blocks 0-3 convert W; blocks 4-7 zero gcur (memset folded in)
    prep_weights<<<8, 256, 0, stream>>>(W[0], W[1], W[2], W[3], WT16, gcur);

    bucket_scatter<<<BLOCKS1, THREADS1, 0, stream>>>(src, dst, gcur, bdata);
    bucket_build<<<PNB, 256, 0, stream>>>(bdata, gcur, offsets, dinv, csr);

    const int MM_GRID = (N_NODES + 63) / 64;          // 1563
    const int AGG_GRID = 4 * FNB;                     // 6252, pass-major

    // layer 1 transform (x fp32 row-major -> GA quarter-major)
    mm_kernel<float><<<MM_GRID, 256, 0, stream>>>(x, WT16, dinv, GA);
    // layer 1..3 aggregate + next transform
    agg4<false><<<AGG_GRID, 256, 0, stream>>>(GA, csr, offsets, dinv, b[0], ACT16);
    mm_kernel<__half><<<MM_GRID, 256, 0, stream>>>(ACT16, WT16 + 1 * DIM * DIM, dinv, GB);
    agg4<false><<<AGG_GRID, 256, 0, stream>>>(GB, csr, offsets, dinv, b[1], ACT16);
    mm_kernel<__half><<<MM_GRID, 256, 0, stream>>>(ACT16, WT16 + 2 * DIM * DIM, dinv, GA);
    agg4<false><<<AGG_GRID, 256, 0, stream>>>(GA, csr, offsets, dinv, b[2], ACT16);
    mm_kernel<__half><<<MM_GRID, 256, 0, stream>>>(ACT16, WT16 + 3 * DIM * DIM, dinv, GB);
    // final aggregate -> fp32 out
    agg4<true><<<AGG_GRID, 256, 0, stream>>>(GB, csr, offsets, dinv, b[3], out);
}